// Round 1
// 173.094 us; speedup vs baseline: 1.0218x; 1.0218x over previous
//
#include <hip/hip_runtime.h>

#define DIM 128
#define BM 128
#define BK 32
#define BINSZ 128      // nodes per coarse bin
#define EPB 2048       // edges per histogram/scatter block

typedef __attribute__((ext_vector_type(8))) short short8;
typedef __attribute__((ext_vector_type(4))) float f32x4;

// bf16 helpers (RNE), values are finite.
__device__ __forceinline__ unsigned short f2bf(float f) {
    unsigned int b = __float_as_uint(f);
    return (unsigned short)((b + 0x7fffu + ((b >> 16) & 1u)) >> 16);
}
__device__ __forceinline__ float bf_lo(unsigned int u) { return __uint_as_float(u << 16); }
__device__ __forceinline__ float bf_hi(unsigned int u) { return __uint_as_float(u & 0xffff0000u); }
__device__ __forceinline__ unsigned int pack2(float a, float b) {
    return (unsigned int)f2bf(a) | ((unsigned int)f2bf(b) << 16);
}
__device__ __forceinline__ uint2 pack4(float4 v) {
    uint2 r; r.x = pack2(v.x, v.y); r.y = pack2(v.z, v.w); return r;
}

// ---------------------------------------------------------------------------
// Per-block dual histogram -> H[blk][bin] (no global atomics).
// Blocks 0..31 additionally convert W -> W_bf (tiny, fully independent).
// ---------------------------------------------------------------------------
__global__ __launch_bounds__(256) void hist_kernel(
        const int* __restrict__ senders, const int* __restrict__ receivers,
        const float4* __restrict__ W4, uint2* __restrict__ Wb4,
        int* __restrict__ Hr, int* __restrict__ Hs, int E, int nbin, int nw4) {
    __shared__ int hr[512], hs[512];
    int t = threadIdx.x;

    // fold W conversion in here (8192 float4 over the first 32 blocks)
    int gi = blockIdx.x * 256 + t;
    if (gi < nw4) Wb4[gi] = pack4(W4[gi]);

    for (int b = t; b < nbin; b += 256) { hr[b] = 0; hs[b] = 0; }
    __syncthreads();
    int base = blockIdx.x * EPB;
    for (int k = 0; k < EPB; k += 256) {
        int e = base + k + t;
        if (e < E) {
            atomicAdd(&hr[receivers[e] >> 7], 1);
            atomicAdd(&hs[senders[e] >> 7], 1);
        }
    }
    __syncthreads();
    size_t ho = (size_t)blockIdx.x * nbin;
    for (int b = t; b < nbin; b += 256) {
        Hr[ho + b] = hr[b];
        Hs[ho + b] = hs[b];
    }
}

// ---------------------------------------------------------------------------
// Per-bin scan over blocks: H[blk][bin] -> exclusive prefix (in place) and
// per-bin totals. One block per bin, handles R and S sides.
// ---------------------------------------------------------------------------
__global__ __launch_bounds__(512) void scan_bins_kernel(
        int* __restrict__ Hr, int* __restrict__ Hs,
        int* __restrict__ tot_r, int* __restrict__ tot_s,
        int NAB, int nbin) {
    __shared__ int sr[512], ss[512];
    int b = blockIdx.x, t = threadIdx.x;
    int vr = (t < NAB) ? Hr[(size_t)t * nbin + b] : 0;
    int vs = (t < NAB) ? Hs[(size_t)t * nbin + b] : 0;
    sr[t] = vr; ss[t] = vs;
    __syncthreads();
    for (int off = 1; off < 512; off <<= 1) {
        int ur = (t >= off) ? sr[t - off] : 0;
        int us = (t >= off) ? ss[t - off] : 0;
        __syncthreads();
        sr[t] += ur; ss[t] += us;
        __syncthreads();
    }
    if (t < NAB) {
        Hr[(size_t)t * nbin + b] = sr[t] - vr;   // exclusive prefix
        Hs[(size_t)t * nbin + b] = ss[t] - vs;
    }
    if (t == 511) { tot_r[b] = sr[511]; tot_s[b] = ss[511]; }
}

// ---------------------------------------------------------------------------
// Scan per-bin totals -> global bin bases; also row_start[N] = E.
// ---------------------------------------------------------------------------
__global__ __launch_bounds__(512) void scan_base_kernel(
        const int* __restrict__ tot_r, const int* __restrict__ tot_s,
        int* __restrict__ base_r, int* __restrict__ base_s,
        int* __restrict__ row_start, int nbin, int N, int E) {
    __shared__ int sr[512], ss[512];
    int t = threadIdx.x;
    int vr = (t < nbin) ? tot_r[t] : 0;
    int vs = (t < nbin) ? tot_s[t] : 0;
    sr[t] = vr; ss[t] = vs;
    __syncthreads();
    for (int off = 1; off < 512; off <<= 1) {
        int ur = (t >= off) ? sr[t - off] : 0;
        int us = (t >= off) ? ss[t - off] : 0;
        __syncthreads();
        sr[t] += ur; ss[t] += us;
        __syncthreads();
    }
    if (t < nbin) {
        base_r[t] = sr[t] - vr;
        base_s[t] = ss[t] - vs;
    }
    if (t == 0) { base_r[nbin] = E; base_s[nbin] = E; row_start[N] = E; }
}

// ---------------------------------------------------------------------------
// Scatter into coarse buckets. Cursors = base[b] + P[blk][b]; LDS atomics
// only, plain global stores. Receiver entry packs ((r&127)<<16)|s.
// ---------------------------------------------------------------------------
__global__ __launch_bounds__(256) void scatter_kernel(
        const int* __restrict__ senders, const int* __restrict__ receivers,
        const int* __restrict__ Hr, const int* __restrict__ Hs,
        const int* __restrict__ base_r, const int* __restrict__ base_s,
        unsigned int* __restrict__ bucket_r, int* __restrict__ bucket_s,
        int E, int nbin) {
    __shared__ int br_[512], bs_[512];
    int t = threadIdx.x;
    size_t ho = (size_t)blockIdx.x * nbin;
    for (int b = t; b < nbin; b += 256) {
        br_[b] = base_r[b] + Hr[ho + b];
        bs_[b] = base_s[b] + Hs[ho + b];
    }
    __syncthreads();
    int base = blockIdx.x * EPB;
    for (int k = 0; k < EPB; k += 256) {
        int e = base + k + t;
        if (e < E) {
            int s = senders[e], r = receivers[e];
            int pr = atomicAdd(&br_[r >> 7], 1);
            bucket_r[pr] = ((unsigned int)(r & 127) << 16) | (unsigned int)s;
            int ps = atomicAdd(&bs_[s >> 7], 1);
            bucket_s[ps] = s;
        }
    }
}

// ---------------------------------------------------------------------------
// Fused fine pass (one block per bin): receiver fine-sort -> row_start +
// edge_src; sender fine-count (LDS only) -> fs; and x conversion fused:
// reads x (f32), writes BOTH x_bf (plain bf16) and xs = bf16(x * sc_r).
// This replaces the former standalone convert kernel (one fewer pass over x).
// ---------------------------------------------------------------------------
__global__ __launch_bounds__(256) void fine_kernel(
        const unsigned int* __restrict__ bucket_r,
        const int* __restrict__ bucket_s,
        const int* __restrict__ base_r,
        const int* __restrict__ base_s,
        const float4* __restrict__ x4,     // [N][32] f32
        uint2* __restrict__ xb2,           // out: [NP][32] bf16
        int* __restrict__ edge_src,
        int* __restrict__ row_start,
        float* __restrict__ fs,
        uint2* __restrict__ xs2,           // out: [NP][32] bf16 prescaled
        int N) {
    __shared__ int fine[BINSZ], fstart[BINSZ], cs[BINSZ];
    __shared__ float scs[BINSZ];
    int b = blockIdx.x, t = threadIdx.x;
    if (t < BINSZ) { fine[t] = 0; cs[t] = 0; }
    __syncthreads();

    int loR = base_r[b], hiR = base_r[b + 1];
    int loS = base_s[b], hiS = base_s[b + 1];
    for (int i = loR + t; i < hiR; i += 256)
        atomicAdd(&fine[bucket_r[i] >> 16], 1);
    for (int i = loS + t; i < hiS; i += 256)
        atomicAdd(&cs[bucket_s[i] & 127], 1);
    __syncthreads();

    if (t < BINSZ) fstart[t] = fine[t];
    __syncthreads();
    for (int off = 1; off < BINSZ; off <<= 1) {
        int u = (t < BINSZ && t >= off) ? fstart[t - off] : 0;
        __syncthreads();
        if (t < BINSZ) fstart[t] += u;
        __syncthreads();
    }
    if (t < BINSZ) {
        int excl = fstart[t] - fine[t];
        int node = b * BINSZ + t;
        float od = (float)(fine[t] + 1);
        float sc = rsqrtf(od);
        scs[t] = sc;
        if (node < N) {
            row_start[node] = loR + excl;
            fs[node] = rsqrtf((float)(cs[t] + 1)) / od;
        }
        fstart[t] = excl;   // becomes the scatter cursor
    }
    __syncthreads();

    for (int i = loR + t; i < hiR; i += 256) {
        unsigned int u = bucket_r[i];
        int pos = atomicAdd(&fstart[u >> 16], 1);
        edge_src[loR + pos] = (int)(u & 0xFFFFu);
    }

    // Convert + prescale this bin's 128 rows: 128 x 32 float4 -> 2x uint2.
    int nrow0 = b * BINSZ;
    for (int idx = t; idx < BINSZ * 32; idx += 256) {
        int row = idx >> 5, c = idx & 31;
        int node = nrow0 + row;
        if (node < N) {
            float4 v = x4[(size_t)node * 32 + c];
            float sc = scs[row];
            xb2[(size_t)node * 32 + c] = pack4(v);
            float4 vs;
            vs.x = v.x * sc; vs.y = v.y * sc; vs.z = v.z * sc; vs.w = v.w * sc;
            xs2[(size_t)node * 32 + c] = pack4(vs);
        }
    }
}

// ---------------------------------------------------------------------------
// Gather: agg[n] = (sum_{src in CSR[n]} xs[src] + xs[n]) * fs[n].
// 4 nodes per wave: 16-lane group per node, lane owns 8 dims via dwordx4.
// One load instruction now covers 4 source rows (1 KiB) instead of 1 row
// (256 B) -> ~4x fewer VMEM instructions, 16 loads in flight per wave.
// ---------------------------------------------------------------------------
__global__ __launch_bounds__(256) void gather_kernel(
        const uint4* __restrict__ xs4,     // [NP][16]
        const int* __restrict__ edge_src,
        const int* __restrict__ row_start, // [N+1]
        const float* __restrict__ fs,      // [N]
        uint4* __restrict__ aggb4,         // [NP][16]
        int N) {
    int lane = threadIdx.x & 63;
    int grp  = lane >> 4;          // 0..3: node within wave
    int gl   = lane & 15;          // lane within group: dims [gl*8, gl*8+8)
    int wid  = (blockIdx.x * blockDim.x + threadIdx.x) >> 6;
    int n    = wid * 4 + grp;
    bool valid = (n < N);

    int start = 0, deg = 0;
    if (valid) {
        start = row_start[n];
        deg   = row_start[n + 1] - start;
    }
    // wave-uniform loop bound = max deg over the 4 groups
    int md = deg;
    md = max(md, __shfl_xor(md, 16));
    md = max(md, __shfl_xor(md, 32));

    float a[8];
#pragma unroll
    for (int q = 0; q < 8; q++) a[q] = 0.f;

    for (int base = 0; base < md; base += 16) {
        int e = base + gl;
        int src = -1;
        if (e < deg) src = edge_src[start + e];
#pragma unroll
        for (int j = 0; j < 16; j++) {
            int s = __shfl(src, (grp << 4) | j);
            if (s >= 0) {
                uint4 u = xs4[(size_t)s * 16 + gl];
                a[0] += bf_lo(u.x); a[1] += bf_hi(u.x);
                a[2] += bf_lo(u.y); a[3] += bf_hi(u.y);
                a[4] += bf_lo(u.z); a[5] += bf_hi(u.z);
                a[6] += bf_lo(u.w); a[7] += bf_hi(u.w);
            }
        }
    }

    if (valid) {
        float f = fs[n];
        uint4 u = xs4[(size_t)n * 16 + gl];   // self loop
        a[0] = (a[0] + bf_lo(u.x)) * f; a[1] = (a[1] + bf_hi(u.x)) * f;
        a[2] = (a[2] + bf_lo(u.y)) * f; a[3] = (a[3] + bf_hi(u.y)) * f;
        a[4] = (a[4] + bf_lo(u.z)) * f; a[5] = (a[5] + bf_hi(u.z)) * f;
        a[6] = (a[6] + bf_lo(u.w)) * f; a[7] = (a[7] + bf_hi(u.w)) * f;
        uint4 o;
        o.x = pack2(a[0], a[1]); o.y = pack2(a[2], a[3]);
        o.z = pack2(a[4], a[5]); o.w = pack2(a[6], a[7]);
        aggb4[(size_t)n * 16 + gl] = o;
    }
}

// ---------------------------------------------------------------------------
// MFMA bf16 GEMM, 512 threads: out = [x_bf | agg_bf] @ W_bf^T + b.
// Block 128x128, 8 waves in 2x4; each wave 4x2 tiles of 16x16x32 mfma.
// C/D layout: col = lane&15, row = (lane>>4)*4 + reg.
// ---------------------------------------------------------------------------
__global__ __launch_bounds__(512) void gemm_kernel(
        const unsigned short* __restrict__ x_bf,   // [NP][128]
        const unsigned short* __restrict__ agg_bf, // [NP][128]
        const unsigned short* __restrict__ W_bf,   // [128][256]
        const float* __restrict__ bias,
        float* __restrict__ out, int N) {
    __shared__ unsigned short As[BM * BK];
    __shared__ unsigned short Bs[DIM * BK];

    int t    = threadIdx.x;
    int lane = t & 63;
    int w    = t >> 6;           // 0..7
    int wr   = w >> 2, wc = w & 3;
    int row0 = blockIdx.x * BM;

    f32x4 acc[4][2];
#pragma unroll
    for (int i = 0; i < 4; i++)
#pragma unroll
        for (int j = 0; j < 2; j++) acc[i][j] = (f32x4){0.f, 0.f, 0.f, 0.f};

    for (int kt = 0; kt < 8; kt++) {
        const unsigned short* src = (kt < 4) ? x_bf : agg_bf;
        int k0 = (kt & 3) * BK;
        {   // stage A: 128 rows x 32 k in one 512-thread pass
            int row = t >> 2, ch = t & 3;
            uint4 v = *(const uint4*)&src[(size_t)(row0 + row) * 128 + k0 + ch * 8];
            *(uint4*)&As[row * BK + ch * 8] = v;
        }
        {   // stage B: 128 n x 32 k
            int n = t >> 2, ch = t & 3;
            uint4 v = *(const uint4*)&W_bf[(size_t)n * 256 + kt * BK + ch * 8];
            *(uint4*)&Bs[n * BK + ch * 8] = v;
        }
        __syncthreads();

        short8 a[4], b[2];
#pragma unroll
        for (int i = 0; i < 4; i++)
            a[i] = *(const short8*)&As[(wr * 64 + i * 16 + (lane & 15)) * BK + (lane >> 4) * 8];
#pragma unroll
        for (int j = 0; j < 2; j++)
            b[j] = *(const short8*)&Bs[(wc * 32 + j * 16 + (lane & 15)) * BK + (lane >> 4) * 8];
#pragma unroll
        for (int i = 0; i < 4; i++)
#pragma unroll
            for (int j = 0; j < 2; j++)
                acc[i][j] = __builtin_amdgcn_mfma_f32_16x16x32_bf16(a[i], b[j], acc[i][j], 0, 0, 0);
        __syncthreads();
    }

    int cq = lane >> 4;
    int cl = lane & 15;
#pragma unroll
    for (int j = 0; j < 2; j++) {
        int col = wc * 32 + j * 16 + cl;
        float bb = bias[col];
#pragma unroll
        for (int i = 0; i < 4; i++) {
            int rbase = row0 + wr * 64 + i * 16 + cq * 4;
#pragma unroll
            for (int r = 0; r < 4; r++) {
                int row = rbase + r;
                if (row < N) out[(size_t)row * DIM + col] = acc[i][j][r] + bb;
            }
        }
    }
}

// ---------------------------------------------------------------------------
// Launch
// ---------------------------------------------------------------------------
extern "C" void kernel_launch(void* const* d_in, const int* in_sizes, int n_in,
                              void* d_out, int out_size, void* d_ws, size_t ws_size,
                              hipStream_t stream) {
    const float* x         = (const float*)d_in[0];
    const int*   senders   = (const int*)d_in[1];
    const int*   receivers = (const int*)d_in[2];
    const float* W         = (const float*)d_in[4];
    const float* bias      = (const float*)d_in[5];
    float*       out       = (float*)d_out;

    int N    = in_sizes[0] / DIM;              // 50000
    int E    = in_sizes[1];                    // 625000
    int nbin = (N + BINSZ - 1) / BINSZ;        // 391  (<= 512)
    int NAB  = (E + EPB - 1) / EPB;            // 306  (<= 512)
    int NP   = ((N + BM - 1) / BM) * BM;       // 50048

    // Workspace layout, 256B-aligned chunks. Hr/Hs and both sort buckets
    // ALIAS the agg_bf region: they are dead before gather writes agg
    // (hist/scan/scatter/fine all precede).
    char* ws = (char*)d_ws;
    size_t off = 0;
    #define WS_ALLOC(ptrtype, name, bytes) \
        ptrtype name = (ptrtype)(ws + off); off += (((size_t)(bytes)) + 255) & ~(size_t)255;
    WS_ALLOC(int*,            tot_r,     (size_t)nbin * 4)
    WS_ALLOC(int*,            tot_s,     (size_t)nbin * 4)
    WS_ALLOC(int*,            base_r,    (size_t)(nbin + 1) * 4)
    WS_ALLOC(int*,            base_s,    (size_t)(nbin + 1) * 4)
    WS_ALLOC(int*,            row_start, (size_t)(N + 1) * 4)
    WS_ALLOC(float*,          fs,        (size_t)N * 4)
    WS_ALLOC(int*,            edge_src,  (size_t)E * 4)
    WS_ALLOC(unsigned short*, x_bf,      (size_t)NP * DIM * 2)
    WS_ALLOC(unsigned short*, xs_bf,     (size_t)NP * DIM * 2)
    WS_ALLOC(unsigned short*, agg_bf,    (size_t)NP * DIM * 2)
    WS_ALLOC(unsigned short*, W_bf,      (size_t)DIM * 256 * 2)
    #undef WS_ALLOC

    // Aliases inside agg_bf (12.81 MB >= 2.5 + 2.5 + 0.48 + 0.48 MB):
    size_t eb = ((size_t)E * 4 + 255) & ~(size_t)255;
    size_t hb = ((size_t)NAB * nbin * 4 + 255) & ~(size_t)255;
    unsigned int* bucket_r = (unsigned int*)agg_bf;
    int*          bucket_s = (int*)((char*)agg_bf + eb);
    int*          Hr       = (int*)((char*)agg_bf + 2 * eb);
    int*          Hs       = (int*)((char*)agg_bf + 2 * eb + hb);

    int nw4 = DIM * 256 / 4;   // 8192 float4 of W

    hist_kernel<<<NAB, 256, 0, stream>>>(senders, receivers,
                                         (const float4*)W, (uint2*)W_bf,
                                         Hr, Hs, E, nbin, nw4);
    scan_bins_kernel<<<nbin, 512, 0, stream>>>(Hr, Hs, tot_r, tot_s, NAB, nbin);
    scan_base_kernel<<<1, 512, 0, stream>>>(tot_r, tot_s, base_r, base_s,
                                            row_start, nbin, N, E);
    scatter_kernel<<<NAB, 256, 0, stream>>>(senders, receivers, Hr, Hs,
                                            base_r, base_s, bucket_r, bucket_s, E, nbin);
    fine_kernel<<<nbin, 256, 0, stream>>>(bucket_r, bucket_s, base_r, base_s,
                                          (const float4*)x, (uint2*)x_bf,
                                          edge_src, row_start, fs,
                                          (uint2*)xs_bf, N);
    int nwave = (N + 3) / 4;
    gather_kernel<<<(nwave * 64 + 255) / 256, 256, 0, stream>>>(
        (const uint4*)xs_bf, edge_src, row_start, fs,
        (uint4*)agg_bf, N);
    gemm_kernel<<<(N + BM - 1) / BM, 512, 0, stream>>>(
        x_bf, agg_bf, W_bf, bias, out, N);
}